// Round 1
// baseline (262.818 us; speedup 1.0000x reference)
//
#include <hip/hip_runtime.h>

typedef float f4 __attribute__((ext_vector_type(4)));

#define NPTS 262144
#define CDIM 48
#define DDIM 32
#define KDIM 4
#define G0 512
#define G1 512
#define G2 128

// ws layout (float offsets)
#define WF_OFF 0                                   // [3][4][48][32] = 18432
#define T0_OFF 18432                               // [4][512][48]   = 98304
#define T1_OFF (18432 + 98304)                     // [4][512][48]   = 98304
#define T2_OFF (18432 + 98304 + 98304)             // [4][128][48]   = 24576
// total = 239616 floats = 958464 bytes

__global__ void pack_kernel(const int* __restrict__ topk_id,
                            const float* __restrict__ tw,
                            const float* __restrict__ line0,
                            const float* __restrict__ line1,
                            const float* __restrict__ line2,
                            const float* __restrict__ feat0,
                            const float* __restrict__ feat1,
                            const float* __restrict__ feat2,
                            float* __restrict__ ws) {
    int tid = blockIdx.x * blockDim.x + threadIdx.x;
    int stride = gridDim.x * blockDim.x;

    // Wf[i][k][c][d] = tw[k] * feat_i[topk_id[k]][c][d]
    for (int idx = tid; idx < 3 * KDIM * CDIM * DDIM; idx += stride) {
        int d = idx & (DDIM - 1);
        int c = (idx / DDIM) % CDIM;
        int k = (idx / (DDIM * CDIM)) & (KDIM - 1);
        int i = idx / (DDIM * CDIM * KDIM);
        const float* f = (i == 0) ? feat0 : (i == 1) ? feat1 : feat2;
        ws[WF_OFF + idx] = tw[k] * f[((size_t)topk_id[k] * CDIM + c) * DDIM + d];
    }
    // T0/T1: [k][g][c] <- line[id[k]][c][g]
    for (int idx = tid; idx < KDIM * G0 * CDIM; idx += stride) {
        int c = idx % CDIM;
        int g = (idx / CDIM) % G0;
        int k = idx / (CDIM * G0);
        int src = (topk_id[k] * CDIM + c) * G0 + g;
        ws[T0_OFF + idx] = line0[src];
        ws[T1_OFF + idx] = line1[src];
    }
    // T2
    for (int idx = tid; idx < KDIM * G2 * CDIM; idx += stride) {
        int c = idx % CDIM;
        int g = (idx / CDIM) % G2;
        int k = idx / (CDIM * G2);
        ws[T2_OFF + idx] = line2[(topk_id[k] * CDIM + c) * G2 + g];
    }
}

__global__ __launch_bounds__(256) void main_kernel(const float* __restrict__ pts,
                                                   const float* __restrict__ ws,
                                                   float* __restrict__ out) {
    int n = blockIdx.x * 256 + threadIdx.x;

    float px = pts[n * 3 + 0];
    float py = pts[n * 3 + 1];
    float pz = pts[n * 3 + 2];

    float pos0 = (px + 1.0f) * 0.5f * (float)(G0 - 1);
    int i00 = min(max((int)floorf(pos0), 0), G0 - 2);
    float w0 = pos0 - (float)i00;

    float pos1 = (py + 1.0f) * 0.5f * (float)(G1 - 1);
    int i01 = min(max((int)floorf(pos1), 0), G1 - 2);
    float w1 = pos1 - (float)i01;

    float pos2 = (pz + 1.0f) * 0.5f * (float)(G2 - 1);
    int i02 = min(max((int)floorf(pos2), 0), G2 - 2);
    float w2 = pos2 - (float)i02;

    const float* Wf = ws + WF_OFF;
    const float* T0 = ws + T0_OFF;
    const float* T1 = ws + T1_OFF;
    const float* T2 = ws + T2_OFF;

    float acc[96];
#pragma unroll
    for (int i = 0; i < 96; ++i) acc[i] = 0.0f;

    for (int k = 0; k < KDIM; ++k) {
        const float* r0 = T0 + (k * G0 + i00) * CDIM;
        const float* r1 = T1 + (k * G1 + i01) * CDIM;
        const float* r2 = T2 + (k * G2 + i02) * CDIM;
        const float* f0base = Wf + ((0 * KDIM + k) * CDIM) * DDIM;
        const float* f1base = Wf + ((1 * KDIM + k) * CDIM) * DDIM;
        const float* f2base = Wf + ((2 * KDIM + k) * CDIM) * DDIM;

        for (int cq = 0; cq < CDIM / 4; ++cq) {
            f4 a0 = *(const f4*)(r0 + cq * 4);
            f4 b0 = *(const f4*)(r0 + CDIM + cq * 4);
            f4 a1 = *(const f4*)(r1 + cq * 4);
            f4 b1 = *(const f4*)(r1 + CDIM + cq * 4);
            f4 a2 = *(const f4*)(r2 + cq * 4);
            f4 b2 = *(const f4*)(r2 + CDIM + cq * 4);

#pragma unroll
            for (int cc = 0; cc < 4; ++cc) {
                float c0 = a0[cc] * (1.0f - w0) + b0[cc] * w0;
                float c1 = a1[cc] * (1.0f - w1) + b1[cc] * w1;
                float c2 = a2[cc] * (1.0f - w2) + b2[cc] * w2;
                float s01 = c0 * c1;
                float s02 = c0 * c2;
                float s12 = c1 * c2;
                int c = cq * 4 + cc;
                const f4* f0 = (const f4*)(f0base + c * DDIM);
                const f4* f1 = (const f4*)(f1base + c * DDIM);
                const f4* f2 = (const f4*)(f2base + c * DDIM);
#pragma unroll
                for (int dq = 0; dq < 8; ++dq) {
                    f4 v0 = f0[dq];
                    f4 v1 = f1[dq];
                    f4 v2 = f2[dq];
                    acc[dq * 4 + 0] += s01 * v0[0];
                    acc[dq * 4 + 1] += s01 * v0[1];
                    acc[dq * 4 + 2] += s01 * v0[2];
                    acc[dq * 4 + 3] += s01 * v0[3];
                    acc[32 + dq * 4 + 0] += s02 * v1[0];
                    acc[32 + dq * 4 + 1] += s02 * v1[1];
                    acc[32 + dq * 4 + 2] += s02 * v1[2];
                    acc[32 + dq * 4 + 3] += s02 * v1[3];
                    acc[64 + dq * 4 + 0] += s12 * v2[0];
                    acc[64 + dq * 4 + 1] += s12 * v2[1];
                    acc[64 + dq * 4 + 2] += s12 * v2[2];
                    acc[64 + dq * 4 + 3] += s12 * v2[3];
                }
            }
        }
    }

    float* o = out + (size_t)n * 96;
#pragma unroll
    for (int q = 0; q < 24; ++q) {
        f4 v;
        v[0] = acc[q * 4 + 0];
        v[1] = acc[q * 4 + 1];
        v[2] = acc[q * 4 + 2];
        v[3] = acc[q * 4 + 3];
        *(f4*)(o + q * 4) = v;
    }
}

extern "C" void kernel_launch(void* const* d_in, const int* in_sizes, int n_in,
                              void* d_out, int out_size, void* d_ws, size_t ws_size,
                              hipStream_t stream) {
    const float* pts = (const float*)d_in[0];
    const int* topk_id = (const int*)d_in[1];
    const float* tw = (const float*)d_in[2];
    const float* line0 = (const float*)d_in[3];
    const float* line1 = (const float*)d_in[4];
    const float* line2 = (const float*)d_in[5];
    const float* feat0 = (const float*)d_in[6];
    const float* feat1 = (const float*)d_in[7];
    const float* feat2 = (const float*)d_in[8];
    float* out = (float*)d_out;
    float* ws = (float*)d_ws;

    pack_kernel<<<256, 256, 0, stream>>>(topk_id, tw, line0, line1, line2,
                                         feat0, feat1, feat2, ws);
    main_kernel<<<NPTS / 256, 256, 0, stream>>>(pts, ws, out);
}

// Round 3
// 112.752 us; speedup vs baseline: 2.3310x; 2.3310x over previous
//
#include <hip/hip_runtime.h>

typedef float f4 __attribute__((ext_vector_type(4)));
typedef float f32x4 __attribute__((ext_vector_type(4)));
typedef short bf16x8 __attribute__((ext_vector_type(8)));
typedef unsigned int u32x4 __attribute__((ext_vector_type(4)));

#define NPTS 262144
#define CDIM 48
#define DDIM 32
#define KDIM 4
#define G0 512
#define G1 512
#define G2 128

// ws layout (in float slots):
// [0, 9216)          : WB — 18432 bf16 (ushort) MFMA B-fragments = 36864 B
//                      frag f = (plane*2 + dtile)*6 + kt ; entry f*512 + lane*8 + j
//                      value = tw[k] * feat_plane[id[k]][c][d],
//                      kc = kt*32 + (lane>>4)*8 + j, k=kc/48, c=kc%48, d=dtile*16+(lane&15)
#define T0_OFF 9216                     // [4][512][48] f32
#define T1_OFF (9216 + 98304)           // [4][512][48] f32
#define T2_OFF (9216 + 2 * 98304)       // [4][128][48] f32
// total = 230400 floats = 921600 B

static __forceinline__ __device__ short f2b(float f) {
    __bf16 b = (__bf16)f;   // RNE
    return __builtin_bit_cast(short, b);
}

__global__ void pack_kernel(const int* __restrict__ topk_id,
                            const float* __restrict__ tw,
                            const float* __restrict__ line0,
                            const float* __restrict__ line1,
                            const float* __restrict__ line2,
                            const float* __restrict__ feat0,
                            const float* __restrict__ feat1,
                            const float* __restrict__ feat2,
                            float* __restrict__ ws) {
    int tid = blockIdx.x * blockDim.x + threadIdx.x;
    int stride = gridDim.x * blockDim.x;
    unsigned short* WB = (unsigned short*)ws;

    // B-fragments in exact MFMA lane order, bf16, weight folded in
    for (int idx = tid; idx < 3 * 2 * 6 * 64 * 8; idx += stride) {
        int j = idx & 7;
        int l = (idx >> 3) & 63;
        int kt = (idx >> 9) % 6;
        int t = (idx / 3072) % 2;
        int i = idx / 6144;
        int kc = kt * 32 + (l >> 4) * 8 + j;
        int k = kc / 48;
        int c = kc - k * 48;
        int d = t * 16 + (l & 15);
        const float* f = (i == 0) ? feat0 : (i == 1) ? feat1 : feat2;
        float val = tw[k] * f[((size_t)topk_id[k] * CDIM + c) * DDIM + d];
        WB[idx] = (unsigned short)f2b(val);
    }
    // T0/T1: [k][g][c] <- line[id[k]][c][g]
    for (int idx = tid; idx < KDIM * G0 * CDIM; idx += stride) {
        int c = idx % CDIM;
        int g = (idx / CDIM) % G0;
        int k = idx / (CDIM * G0);
        int src = (topk_id[k] * CDIM + c) * G0 + g;
        ws[T0_OFF + idx] = line0[src];
        ws[T1_OFF + idx] = line1[src];
    }
    // T2
    for (int idx = tid; idx < KDIM * G2 * CDIM; idx += stride) {
        int c = idx % CDIM;
        int g = (idx / CDIM) % G2;
        int k = idx / (CDIM * G2);
        ws[T2_OFF + idx] = line2[(topk_id[k] * CDIM + c) * G2 + g];
    }
}

__global__ __launch_bounds__(256) void main_kernel(const float* __restrict__ pts,
                                                   const float* __restrict__ ws,
                                                   float* __restrict__ out) {
    __shared__ __align__(16) unsigned short sWB[18432];   // 36864 B
    {
        const u32x4* src = (const u32x4*)ws;
        u32x4* dst = (u32x4*)sWB;
        // 36864 B / 16 B = 2304 vector copies (was 1152 — the NaN bug)
        for (int i = threadIdx.x; i < 2304; i += 256) dst[i] = src[i];
    }
    __syncthreads();

    const int lane = threadIdx.x & 63;
    const int wave = threadIdx.x >> 6;
    const int row = lane & 15;     // d-col selector at C-write; A-row (point) in tile
    const int h = lane >> 4;       // k-chunk selector
    const int base = blockIdx.x * 64 + wave * 16;
    const int p = base + row;

    const float px = pts[p * 3 + 0];
    const float py = pts[p * 3 + 1];
    const float pz = pts[p * 3 + 2];

    float pos0 = (px + 1.0f) * (0.5f * (float)(G0 - 1));
    int i00 = min(max((int)floorf(pos0), 0), G0 - 2);
    float w0 = pos0 - (float)i00, om0 = 1.0f - w0;

    float pos1 = (py + 1.0f) * (0.5f * (float)(G1 - 1));
    int i01 = min(max((int)floorf(pos1), 0), G1 - 2);
    float w1 = pos1 - (float)i01, om1 = 1.0f - w1;

    float pos2 = (pz + 1.0f) * (0.5f * (float)(G2 - 1));
    int i02 = min(max((int)floorf(pos2), 0), G2 - 2);
    float w2 = pos2 - (float)i02, om2 = 1.0f - w2;

    const float* T0 = ws + T0_OFF;
    const float* T1 = ws + T1_OFF;
    const float* T2 = ws + T2_OFF;
    const bf16x8* wb = (const bf16x8*)sWB;   // 16 B per entry, 64 entries per frag

    f32x4 acc00 = {0.f, 0.f, 0.f, 0.f}, acc01 = acc00;
    f32x4 acc10 = acc00, acc11 = acc00;
    f32x4 acc20 = acc00, acc21 = acc00;

#pragma unroll
    for (int kt = 0; kt < 6; ++kt) {
        int kc = kt * 32 + h * 8;
        int k = kc / 48;
        int c = kc - k * 48;

        const float* r0 = T0 + ((k * G0 + i00) * CDIM + c);
        const float* r1 = T1 + ((k * G1 + i01) * CDIM + c);
        const float* r2 = T2 + ((k * G2 + i02) * CDIM + c);

        f4 a0l = *(const f4*)r0,          a0h = *(const f4*)(r0 + 4);
        f4 b0l = *(const f4*)(r0 + CDIM), b0h = *(const f4*)(r0 + CDIM + 4);
        f4 a1l = *(const f4*)r1,          a1h = *(const f4*)(r1 + 4);
        f4 b1l = *(const f4*)(r1 + CDIM), b1h = *(const f4*)(r1 + CDIM + 4);
        f4 a2l = *(const f4*)r2,          a2h = *(const f4*)(r2 + 4);
        f4 b2l = *(const f4*)(r2 + CDIM), b2h = *(const f4*)(r2 + CDIM + 4);

        f4 x0l = a0l * om0 + b0l * w0, x0h = a0h * om0 + b0h * w0;
        f4 x1l = a1l * om1 + b1l * w1, x1h = a1h * om1 + b1h * w1;
        f4 x2l = a2l * om2 + b2l * w2, x2h = a2h * om2 + b2h * w2;

        f4 s01l = x0l * x1l, s01h = x0h * x1h;
        f4 s02l = x0l * x2l, s02h = x0h * x2h;
        f4 s12l = x1l * x2l, s12h = x1h * x2h;

        bf16x8 a01, a02, a12;
#pragma unroll
        for (int jj = 0; jj < 4; ++jj) {
            a01[jj] = f2b(s01l[jj]); a01[4 + jj] = f2b(s01h[jj]);
            a02[jj] = f2b(s02l[jj]); a02[4 + jj] = f2b(s02h[jj]);
            a12[jj] = f2b(s12l[jj]); a12[4 + jj] = f2b(s12h[jj]);
        }

        acc00 = __builtin_amdgcn_mfma_f32_16x16x32_bf16(a01, wb[(0 * 6 + kt) * 64 + lane], acc00, 0, 0, 0);
        acc01 = __builtin_amdgcn_mfma_f32_16x16x32_bf16(a01, wb[(1 * 6 + kt) * 64 + lane], acc01, 0, 0, 0);
        acc10 = __builtin_amdgcn_mfma_f32_16x16x32_bf16(a02, wb[(2 * 6 + kt) * 64 + lane], acc10, 0, 0, 0);
        acc11 = __builtin_amdgcn_mfma_f32_16x16x32_bf16(a02, wb[(3 * 6 + kt) * 64 + lane], acc11, 0, 0, 0);
        acc20 = __builtin_amdgcn_mfma_f32_16x16x32_bf16(a12, wb[(4 * 6 + kt) * 64 + lane], acc20, 0, 0, 0);
        acc21 = __builtin_amdgcn_mfma_f32_16x16x32_bf16(a12, wb[(5 * 6 + kt) * 64 + lane], acc21, 0, 0, 0);
    }

    // C layout (m89-verified): col = lane&15, row = (lane>>4)*4 + reg
#pragma unroll
    for (int r = 0; r < 4; ++r) {
        size_t o = (size_t)(base + h * 4 + r) * 96 + row;
        out[o + 0]  = acc00[r];
        out[o + 16] = acc01[r];
        out[o + 32] = acc10[r];
        out[o + 48] = acc11[r];
        out[o + 64] = acc20[r];
        out[o + 80] = acc21[r];
    }
}

extern "C" void kernel_launch(void* const* d_in, const int* in_sizes, int n_in,
                              void* d_out, int out_size, void* d_ws, size_t ws_size,
                              hipStream_t stream) {
    const float* pts = (const float*)d_in[0];
    const int* topk_id = (const int*)d_in[1];
    const float* tw = (const float*)d_in[2];
    const float* line0 = (const float*)d_in[3];
    const float* line1 = (const float*)d_in[4];
    const float* line2 = (const float*)d_in[5];
    const float* feat0 = (const float*)d_in[6];
    const float* feat1 = (const float*)d_in[7];
    const float* feat2 = (const float*)d_in[8];
    float* out = (float*)d_out;
    float* ws = (float*)d_ws;

    pack_kernel<<<512, 256, 0, stream>>>(topk_id, tw, line0, line1, line2,
                                         feat0, feat1, feat2, ws);
    main_kernel<<<NPTS / 64, 256, 0, stream>>>(pts, ws, out);
}

// Round 4
// 109.641 us; speedup vs baseline: 2.3971x; 1.0284x over previous
//
#include <hip/hip_runtime.h>

typedef float f4 __attribute__((ext_vector_type(4)));
typedef float f32x4 __attribute__((ext_vector_type(4)));
typedef short bf16x8 __attribute__((ext_vector_type(8)));
typedef unsigned int u32x4 __attribute__((ext_vector_type(4)));

#define NPTS 262144
#define CDIM 48
#define DDIM 32
#define KDIM 4
#define G0 512
#define G1 512
#define G2 128

// ws layout (in float slots):
// [0, 9216)          : WB — 18432 bf16 (ushort) MFMA B-fragments = 36864 B
//                      frag f = (plane*2 + dtile)*6 + kt ; entry f*512 + lane*8 + j
//                      value = tw[k] * feat_plane[id[k]][c][d],
//                      kc = kt*32 + (lane>>4)*8 + j, k=kc/48, c=kc%48, d=dtile*16+(lane&15)
#define T0_OFF 9216                     // [4][512][48] f32
#define T1_OFF (9216 + 98304)           // [4][512][48] f32
#define T2_OFF (9216 + 2 * 98304)       // [4][128][48] f32

static __forceinline__ __device__ short f2b(float f) {
    __bf16 b = (__bf16)f;   // RNE
    return __builtin_bit_cast(short, b);
}

__global__ void pack_kernel(const int* __restrict__ topk_id,
                            const float* __restrict__ tw,
                            const float* __restrict__ line0,
                            const float* __restrict__ line1,
                            const float* __restrict__ line2,
                            const float* __restrict__ feat0,
                            const float* __restrict__ feat1,
                            const float* __restrict__ feat2,
                            float* __restrict__ ws) {
    int tid = blockIdx.x * blockDim.x + threadIdx.x;
    int stride = gridDim.x * blockDim.x;
    unsigned short* WB = (unsigned short*)ws;

    for (int idx = tid; idx < 3 * 2 * 6 * 64 * 8; idx += stride) {
        int j = idx & 7;
        int l = (idx >> 3) & 63;
        int kt = (idx >> 9) % 6;
        int t = (idx / 3072) % 2;
        int i = idx / 6144;
        int kc = kt * 32 + (l >> 4) * 8 + j;
        int k = kc / 48;
        int c = kc - k * 48;
        int d = t * 16 + (l & 15);
        const float* f = (i == 0) ? feat0 : (i == 1) ? feat1 : feat2;
        float val = tw[k] * f[((size_t)topk_id[k] * CDIM + c) * DDIM + d];
        WB[idx] = (unsigned short)f2b(val);
    }
    for (int idx = tid; idx < KDIM * G0 * CDIM; idx += stride) {
        int c = idx % CDIM;
        int g = (idx / CDIM) % G0;
        int k = idx / (CDIM * G0);
        int src = (topk_id[k] * CDIM + c) * G0 + g;
        ws[T0_OFF + idx] = line0[src];
        ws[T1_OFF + idx] = line1[src];
    }
    for (int idx = tid; idx < KDIM * G2 * CDIM; idx += stride) {
        int c = idx % CDIM;
        int g = (idx / CDIM) % G2;
        int k = idx / (CDIM * G2);
        ws[T2_OFF + idx] = line2[(topk_id[k] * CDIM + c) * G2 + g];
    }
}

struct Rows {
    f4 a0l, a0h, b0l, b0h;
    f4 a1l, a1h, b1l, b1h;
    f4 a2l, a2h, b2l, b2h;
};

static __forceinline__ __device__ Rows load_rows(const float* __restrict__ T0,
                                                 const float* __restrict__ T1,
                                                 const float* __restrict__ T2,
                                                 int i00, int i01, int i02,
                                                 int kt, int h) {
    int kc = kt * 32 + h * 8;
    int k = kc / 48;
    int c = kc - k * 48;
    const float* r0 = T0 + ((k * G0 + i00) * CDIM + c);
    const float* r1 = T1 + ((k * G1 + i01) * CDIM + c);
    const float* r2 = T2 + ((k * G2 + i02) * CDIM + c);
    Rows r;
    r.a0l = *(const f4*)r0;          r.a0h = *(const f4*)(r0 + 4);
    r.b0l = *(const f4*)(r0 + CDIM); r.b0h = *(const f4*)(r0 + CDIM + 4);
    r.a1l = *(const f4*)r1;          r.a1h = *(const f4*)(r1 + 4);
    r.b1l = *(const f4*)(r1 + CDIM); r.b1h = *(const f4*)(r1 + CDIM + 4);
    r.a2l = *(const f4*)r2;          r.a2h = *(const f4*)(r2 + 4);
    r.b2l = *(const f4*)(r2 + CDIM); r.b2h = *(const f4*)(r2 + CDIM + 4);
    return r;
}

__global__ __launch_bounds__(512, 4) void main_kernel(const float* __restrict__ pts,
                                                      const float* __restrict__ ws,
                                                      float* __restrict__ out) {
    __shared__ __align__(16) unsigned short sWB[18432];   // 36864 B
    {
        const u32x4* src = (const u32x4*)ws;
        u32x4* dst = (u32x4*)sWB;
        for (int i = threadIdx.x; i < 2304; i += 512) dst[i] = src[i];
    }
    __syncthreads();

    const int lane = threadIdx.x & 63;
    const int wave = threadIdx.x >> 6;
    const int row = lane & 15;
    const int h = lane >> 4;
    const int base = blockIdx.x * 128 + wave * 16;
    const int p = base + row;

    const float px = pts[p * 3 + 0];
    const float py = pts[p * 3 + 1];
    const float pz = pts[p * 3 + 2];

    float pos0 = (px + 1.0f) * (0.5f * (float)(G0 - 1));
    int i00 = min(max((int)floorf(pos0), 0), G0 - 2);
    float w0 = pos0 - (float)i00, om0 = 1.0f - w0;

    float pos1 = (py + 1.0f) * (0.5f * (float)(G1 - 1));
    int i01 = min(max((int)floorf(pos1), 0), G1 - 2);
    float w1 = pos1 - (float)i01, om1 = 1.0f - w1;

    float pos2 = (pz + 1.0f) * (0.5f * (float)(G2 - 1));
    int i02 = min(max((int)floorf(pos2), 0), G2 - 2);
    float w2 = pos2 - (float)i02, om2 = 1.0f - w2;

    const float* T0 = ws + T0_OFF;
    const float* T1 = ws + T1_OFF;
    const float* T2 = ws + T2_OFF;
    const bf16x8* wb = (const bf16x8*)sWB;

    f32x4 acc00 = {0.f, 0.f, 0.f, 0.f}, acc01 = acc00;
    f32x4 acc10 = acc00, acc11 = acc00;
    f32x4 acc20 = acc00, acc21 = acc00;

    // 1-deep software pipeline over kt: issue kt+1's 12 f4 loads before
    // computing kt, so ~12 loads stay in flight per wave.
    Rows cur = load_rows(T0, T1, T2, i00, i01, i02, 0, h);

#pragma unroll
    for (int kt = 0; kt < 6; ++kt) {
        Rows nxt;
        if (kt < 5) nxt = load_rows(T0, T1, T2, i00, i01, i02, kt + 1, h);

        f4 x0l = cur.a0l * om0 + cur.b0l * w0, x0h = cur.a0h * om0 + cur.b0h * w0;
        f4 x1l = cur.a1l * om1 + cur.b1l * w1, x1h = cur.a1h * om1 + cur.b1h * w1;
        f4 x2l = cur.a2l * om2 + cur.b2l * w2, x2h = cur.a2h * om2 + cur.b2h * w2;

        f4 s01l = x0l * x1l, s01h = x0h * x1h;
        f4 s02l = x0l * x2l, s02h = x0h * x2h;
        f4 s12l = x1l * x2l, s12h = x1h * x2h;

        bf16x8 a01, a02, a12;
#pragma unroll
        for (int jj = 0; jj < 4; ++jj) {
            a01[jj] = f2b(s01l[jj]); a01[4 + jj] = f2b(s01h[jj]);
            a02[jj] = f2b(s02l[jj]); a02[4 + jj] = f2b(s02h[jj]);
            a12[jj] = f2b(s12l[jj]); a12[4 + jj] = f2b(s12h[jj]);
        }

        acc00 = __builtin_amdgcn_mfma_f32_16x16x32_bf16(a01, wb[(0 * 6 + kt) * 64 + lane], acc00, 0, 0, 0);
        acc01 = __builtin_amdgcn_mfma_f32_16x16x32_bf16(a01, wb[(1 * 6 + kt) * 64 + lane], acc01, 0, 0, 0);
        acc10 = __builtin_amdgcn_mfma_f32_16x16x32_bf16(a02, wb[(2 * 6 + kt) * 64 + lane], acc10, 0, 0, 0);
        acc11 = __builtin_amdgcn_mfma_f32_16x16x32_bf16(a02, wb[(3 * 6 + kt) * 64 + lane], acc11, 0, 0, 0);
        acc20 = __builtin_amdgcn_mfma_f32_16x16x32_bf16(a12, wb[(4 * 6 + kt) * 64 + lane], acc20, 0, 0, 0);
        acc21 = __builtin_amdgcn_mfma_f32_16x16x32_bf16(a12, wb[(5 * 6 + kt) * 64 + lane], acc21, 0, 0, 0);

        if (kt < 5) cur = nxt;
    }

    // C layout (m89-verified): col = lane&15, row = (lane>>4)*4 + reg
#pragma unroll
    for (int r = 0; r < 4; ++r) {
        size_t o = (size_t)(base + h * 4 + r) * 96 + row;
        out[o + 0]  = acc00[r];
        out[o + 16] = acc01[r];
        out[o + 32] = acc10[r];
        out[o + 48] = acc11[r];
        out[o + 64] = acc20[r];
        out[o + 80] = acc21[r];
    }
}

extern "C" void kernel_launch(void* const* d_in, const int* in_sizes, int n_in,
                              void* d_out, int out_size, void* d_ws, size_t ws_size,
                              hipStream_t stream) {
    const float* pts = (const float*)d_in[0];
    const int* topk_id = (const int*)d_in[1];
    const float* tw = (const float*)d_in[2];
    const float* line0 = (const float*)d_in[3];
    const float* line1 = (const float*)d_in[4];
    const float* line2 = (const float*)d_in[5];
    const float* feat0 = (const float*)d_in[6];
    const float* feat1 = (const float*)d_in[7];
    const float* feat2 = (const float*)d_in[8];
    float* out = (float*)d_out;
    float* ws = (float*)d_ws;

    pack_kernel<<<512, 256, 0, stream>>>(topk_id, tw, line0, line1, line2,
                                         feat0, feat1, feat2, ws);
    main_kernel<<<NPTS / 128, 512, 0, stream>>>(pts, ws, out);
}

// Round 5
// 97.217 us; speedup vs baseline: 2.7034x; 1.1278x over previous
//
#include <hip/hip_runtime.h>

typedef float f4 __attribute__((ext_vector_type(4)));
typedef float f32x4 __attribute__((ext_vector_type(4)));
typedef short bf16x8 __attribute__((ext_vector_type(8)));
typedef unsigned short u16x8 __attribute__((ext_vector_type(8)));
typedef unsigned int u32x4 __attribute__((ext_vector_type(4)));

#define NPTS 262144
#define CDIM 48
#define DDIM 32
#define KDIM 4
#define G0 512
#define G1 512
#define G2 128

// ws layout (ushort slots):
// [0, 18432)   : WB — bf16 MFMA B-fragments (36864 B)
//                frag f = (plane*2 + dtile)*6 + kt ; entry f*512 + lane*8 + j
//                value = tw[k] * feat_plane[id[k]][c][d],
//                kc = kt*32 + (lane>>4)*8 + j, k=kc/48, c=kc%48, d=dtile*16+(lane&15)
// T tables in bf16, layout [k][g][c]:
#define T0_OFF 18432                     // 4*512*48 = 98304
#define T1_OFF (18432 + 98304)           // 98304
#define T2_OFF (18432 + 2 * 98304)       // 4*128*48 = 24576
// total 239616 ushorts = 479232 B

static __forceinline__ __device__ short f2b(float f) {
    __bf16 b = (__bf16)f;   // RNE
    return __builtin_bit_cast(short, b);
}
static __forceinline__ __device__ float b2f(unsigned short u) {
    return __builtin_bit_cast(float, ((unsigned int)u) << 16);
}

__global__ void pack_kernel(const int* __restrict__ topk_id,
                            const float* __restrict__ tw,
                            const float* __restrict__ line0,
                            const float* __restrict__ line1,
                            const float* __restrict__ line2,
                            const float* __restrict__ feat0,
                            const float* __restrict__ feat1,
                            const float* __restrict__ feat2,
                            unsigned short* __restrict__ ws) {
    int tid = blockIdx.x * blockDim.x + threadIdx.x;
    int stride = gridDim.x * blockDim.x;

    // B-fragments in exact MFMA lane order, bf16, weight folded in
    for (int idx = tid; idx < 3 * 2 * 6 * 64 * 8; idx += stride) {
        int j = idx & 7;
        int l = (idx >> 3) & 63;
        int kt = (idx >> 9) % 6;
        int t = (idx / 3072) % 2;
        int i = idx / 6144;
        int kc = kt * 32 + (l >> 4) * 8 + j;
        int k = kc / 48;
        int c = kc - k * 48;
        int d = t * 16 + (l & 15);
        const float* f = (i == 0) ? feat0 : (i == 1) ? feat1 : feat2;
        float val = tw[k] * f[((size_t)topk_id[k] * CDIM + c) * DDIM + d];
        ws[idx] = (unsigned short)f2b(val);
    }
    // T0/T1: [k][g][c] <- bf16(line[id[k]][c][g])
    for (int idx = tid; idx < KDIM * G0 * CDIM; idx += stride) {
        int c = idx % CDIM;
        int g = (idx / CDIM) % G0;
        int k = idx / (CDIM * G0);
        int src = (topk_id[k] * CDIM + c) * G0 + g;
        ws[T0_OFF + idx] = (unsigned short)f2b(line0[src]);
        ws[T1_OFF + idx] = (unsigned short)f2b(line1[src]);
    }
    // T2
    for (int idx = tid; idx < KDIM * G2 * CDIM; idx += stride) {
        int c = idx % CDIM;
        int g = (idx / CDIM) % G2;
        int k = idx / (CDIM * G2);
        ws[T2_OFF + idx] = (unsigned short)f2b(line2[(topk_id[k] * CDIM + c) * G2 + g]);
    }
}

__global__ __launch_bounds__(512, 4) void main_kernel(const float* __restrict__ pts,
                                                      const unsigned short* __restrict__ ws,
                                                      float* __restrict__ out) {
    __shared__ __align__(16) unsigned short sWB[18432];   // 36864 B
    {
        const u32x4* src = (const u32x4*)ws;
        u32x4* dst = (u32x4*)sWB;
        for (int i = threadIdx.x; i < 2304; i += 512) dst[i] = src[i];
    }
    __syncthreads();

    const int lane = threadIdx.x & 63;
    const int wave = threadIdx.x >> 6;
    const int row = lane & 15;
    const int h = lane >> 4;
    const int base = blockIdx.x * 128 + wave * 16;
    const int p = base + row;

    const float px = pts[p * 3 + 0];
    const float py = pts[p * 3 + 1];
    const float pz = pts[p * 3 + 2];

    float pos0 = (px + 1.0f) * (0.5f * (float)(G0 - 1));
    int i00 = min(max((int)floorf(pos0), 0), G0 - 2);
    float w0 = pos0 - (float)i00, om0 = 1.0f - w0;

    float pos1 = (py + 1.0f) * (0.5f * (float)(G1 - 1));
    int i01 = min(max((int)floorf(pos1), 0), G1 - 2);
    float w1 = pos1 - (float)i01, om1 = 1.0f - w1;

    float pos2 = (pz + 1.0f) * (0.5f * (float)(G2 - 1));
    int i02 = min(max((int)floorf(pos2), 0), G2 - 2);
    float w2 = pos2 - (float)i02, om2 = 1.0f - w2;

    const unsigned short* T0 = ws + T0_OFF;
    const unsigned short* T1 = ws + T1_OFF;
    const unsigned short* T2 = ws + T2_OFF;
    const bf16x8* wb = (const bf16x8*)sWB;

    f32x4 acc00 = {0.f, 0.f, 0.f, 0.f}, acc01 = acc00;
    f32x4 acc10 = acc00, acc11 = acc00;
    f32x4 acc20 = acc00, acc21 = acc00;

#pragma unroll
    for (int kt = 0; kt < 6; ++kt) {
        int kc = kt * 32 + h * 8;
        int k = kc / 48;
        int c = kc - k * 48;

        // one 16B load = the lane's full 8-value k-slot (bf16)
        const unsigned short* t0 = T0 + (k * G0 + i00) * CDIM + c;
        const unsigned short* t1 = T1 + (k * G1 + i01) * CDIM + c;
        const unsigned short* t2 = T2 + (k * G2 + i02) * CDIM + c;

        u16x8 a0 = *(const u16x8*)t0, b0 = *(const u16x8*)(t0 + CDIM);
        u16x8 a1 = *(const u16x8*)t1, b1 = *(const u16x8*)(t1 + CDIM);
        u16x8 a2 = *(const u16x8*)t2, b2 = *(const u16x8*)(t2 + CDIM);

        bf16x8 a01, a02, a12;
#pragma unroll
        for (int j = 0; j < 8; ++j) {
            float x0 = b2f(a0[j]) * om0 + b2f(b0[j]) * w0;
            float x1 = b2f(a1[j]) * om1 + b2f(b1[j]) * w1;
            float x2 = b2f(a2[j]) * om2 + b2f(b2[j]) * w2;
            a01[j] = f2b(x0 * x1);
            a02[j] = f2b(x0 * x2);
            a12[j] = f2b(x1 * x2);
        }

        acc00 = __builtin_amdgcn_mfma_f32_16x16x32_bf16(a01, wb[(0 * 6 + kt) * 64 + lane], acc00, 0, 0, 0);
        acc01 = __builtin_amdgcn_mfma_f32_16x16x32_bf16(a01, wb[(1 * 6 + kt) * 64 + lane], acc01, 0, 0, 0);
        acc10 = __builtin_amdgcn_mfma_f32_16x16x32_bf16(a02, wb[(2 * 6 + kt) * 64 + lane], acc10, 0, 0, 0);
        acc11 = __builtin_amdgcn_mfma_f32_16x16x32_bf16(a02, wb[(3 * 6 + kt) * 64 + lane], acc11, 0, 0, 0);
        acc20 = __builtin_amdgcn_mfma_f32_16x16x32_bf16(a12, wb[(4 * 6 + kt) * 64 + lane], acc20, 0, 0, 0);
        acc21 = __builtin_amdgcn_mfma_f32_16x16x32_bf16(a12, wb[(5 * 6 + kt) * 64 + lane], acc21, 0, 0, 0);
    }

    // C layout (m89-verified): col = lane&15, row = (lane>>4)*4 + reg
#pragma unroll
    for (int r = 0; r < 4; ++r) {
        size_t o = (size_t)(base + h * 4 + r) * 96 + row;
        out[o + 0]  = acc00[r];
        out[o + 16] = acc01[r];
        out[o + 32] = acc10[r];
        out[o + 48] = acc11[r];
        out[o + 64] = acc20[r];
        out[o + 80] = acc21[r];
    }
}

extern "C" void kernel_launch(void* const* d_in, const int* in_sizes, int n_in,
                              void* d_out, int out_size, void* d_ws, size_t ws_size,
                              hipStream_t stream) {
    const float* pts = (const float*)d_in[0];
    const int* topk_id = (const int*)d_in[1];
    const float* tw = (const float*)d_in[2];
    const float* line0 = (const float*)d_in[3];
    const float* line1 = (const float*)d_in[4];
    const float* line2 = (const float*)d_in[5];
    const float* feat0 = (const float*)d_in[6];
    const float* feat1 = (const float*)d_in[7];
    const float* feat2 = (const float*)d_in[8];
    float* out = (float*)d_out;
    unsigned short* ws = (unsigned short*)d_ws;

    pack_kernel<<<512, 256, 0, stream>>>(topk_id, tw, line0, line1, line2,
                                         feat0, feat1, feat2, ws);
    main_kernel<<<NPTS / 128, 512, 0, stream>>>(pts, ws, out);
}